// Round 1
// baseline (821.481 us; speedup 1.0000x reference)
//
#include <hip/hip_runtime.h>

// KV cache append: out_k = cat(cached_k, new_k, axis=1), out_v likewise.
// B=4, S=4096, NEW=16, D=4096, fp32. Pure memory-bound streaming copy:
// ~539 MB read + ~539 MB write => roofline ~171 us @ 6.3 TB/s.
//
// Structure: one output ROW (D=4096 floats = 16 KB) per block-iteration.
// 256 threads x 4 float4 each covers the row exactly. All index math
// (tensor select, b/s decompose, source pointer pick) is paid once per
// 16 KB instead of once per 16 B as in the previous flat kernel.
// Grid-stride with 2048 blocks (8/CU on 256 CUs) per Guideline 11.
// Nontemporal loads/stores: zero-reuse 1 GB stream, keep it out of L2.

typedef float f4 __attribute__((ext_vector_type(4)));

constexpr int B_   = 4;
constexpr int S_   = 4096;
constexpr int NEW_ = 16;
constexpr int D_   = 4096;
constexpr int SN_  = S_ + NEW_;                    // 4112 rows/batch in output
constexpr int ROW4 = D_ / 4;                       // 1024 float4 per row
constexpr int ROWS_PER_TENSOR = B_ * SN_;          // 16448
constexpr int TOTAL_ROWS = 2 * ROWS_PER_TENSOR;    // 32896 (k then v)
constexpr long long HALF4 = (long long)ROWS_PER_TENSOR * ROW4;  // float4/tensor

constexpr int BLK  = 256;
constexpr int GRID = 2048;  // 256 CUs x 8 blocks/CU; ~16 rows per block

static_assert(ROW4 == 4 * BLK, "row must be exactly 4 float4 per thread");

__global__ __launch_bounds__(BLK) void kv_append_rows(
    const f4* __restrict__ ck, const f4* __restrict__ cv,
    const f4* __restrict__ nk, const f4* __restrict__ nv,
    f4* __restrict__ out)
{
    const int t = threadIdx.x;

    for (int r = blockIdx.x; r < TOTAL_ROWS; r += gridDim.x) {
        int rr = r;
        const f4* cache = ck;
        const f4* fresh = nk;
        f4* dst = out;
        if (rr >= ROWS_PER_TENSOR) {           // second tensor (v)
            rr -= ROWS_PER_TENSOR;
            cache = cv;
            fresh = nv;
            dst = out + HALF4;
        }

        const int b = rr / SN_;                // const divisor -> magic mul
        const int s = rr - b * SN_;

        // Source row: cached part for s < S, fresh (appended) rows after.
        const f4* src = (s < S_)
            ? cache + (long long)(b * S_ + s) * ROW4
            : fresh + (long long)(b * NEW_ + (s - S_)) * ROW4;
        f4* drow = dst + (long long)rr * ROW4;

        // 4 independent 16B loads in flight, then 4 stores. Perfectly
        // coalesced: 256 lanes x contiguous float4, stride 256 per step.
        f4 v0 = __builtin_nontemporal_load(src + t);
        f4 v1 = __builtin_nontemporal_load(src + t + BLK);
        f4 v2 = __builtin_nontemporal_load(src + t + 2 * BLK);
        f4 v3 = __builtin_nontemporal_load(src + t + 3 * BLK);

        __builtin_nontemporal_store(v0, drow + t);
        __builtin_nontemporal_store(v1, drow + t + BLK);
        __builtin_nontemporal_store(v2, drow + t + 2 * BLK);
        __builtin_nontemporal_store(v3, drow + t + 3 * BLK);
    }
}

extern "C" void kernel_launch(void* const* d_in, const int* in_sizes, int n_in,
                              void* d_out, int out_size, void* d_ws, size_t ws_size,
                              hipStream_t stream) {
    const f4* ck = (const f4*)d_in[0];
    const f4* cv = (const f4*)d_in[1];
    const f4* nk = (const f4*)d_in[2];
    const f4* nv = (const f4*)d_in[3];
    f4* out = (f4*)d_out;

    kv_append_rows<<<GRID, BLK, 0, stream>>>(ck, cv, nk, nv, out);
}